// Round 4
// baseline (417.504 us; speedup 1.0000x reference)
//
#include <hip/hip_runtime.h>
#include <stdint.h>

#define BSZ 2
#define LSEQ 2048
#define DMOD 1024
#define NH 16
#define HDSZ 64

typedef __attribute__((ext_vector_type(8))) short short8;
typedef __attribute__((ext_vector_type(4))) float f32x4;
typedef __attribute__((ext_vector_type(4))) unsigned short u16x4;
typedef __attribute__((ext_vector_type(4))) int i32x4;

#define MFMA16(a, b, c) __builtin_amdgcn_mfma_f32_16x16x32_bf16((a), (b), (c), 0, 0, 0)

__device__ __forceinline__ unsigned short f2bf(float f) {
  union { float f; unsigned u; } x; x.f = f;
  unsigned u = x.u + 0x7fffu + ((x.u >> 16) & 1u);
  return (unsigned short)(u >> 16);
}

// ---------------- fp32 -> bf16 conversion ----------------
__global__ __launch_bounds__(256) void cvt_bf16(const float* __restrict__ in,
                                                unsigned short* __restrict__ out, int n) {
  int i = (blockIdx.x * 256 + threadIdx.x) * 4;
  if (i >= n) return;
  f32x4 v = *(const f32x4*)(in + i);
  u16x4 o;
  o[0] = f2bf(v[0]); o[1] = f2bf(v[1]); o[2] = f2bf(v[2]); o[3] = f2bf(v[3]);
  *(u16x4*)(out + i) = o;
}

// ---------------- mask check: flags[b][qt][kt] = all-nonzero over 128x128 tile ----
__global__ __launch_bounds__(256) void mask_check(const int* __restrict__ mask,
                                                  int* __restrict__ flags) {
  const int kt = blockIdx.x, qt = blockIdx.y, b = blockIdx.z;
  const int tid = threadIdx.x;
  const int r = tid >> 1, c = (tid & 1) * 64;
  const int* mr = mask + (size_t)b * LSEQ * LSEQ + (size_t)(qt * 128 + r) * LSEQ + kt * 128 + c;
  int ok = 1;
#pragma unroll
  for (int j = 0; j < 16; j++) {
    i32x4 v = *(const i32x4*)(mr + j * 4);
    ok &= (v[0] != 0) & (v[1] != 0) & (v[2] != 0) & (v[3] != 0);
  }
  __shared__ int red[4];
  unsigned long long vote = __ballot(ok);
  if ((tid & 63) == 0) red[tid >> 6] = (vote == ~0ull) ? 1 : 0;
  __syncthreads();
  if (tid == 0) flags[(b * 16 + qt) * 16 + kt] = red[0] & red[1] & red[2] & red[3];
}

// ---------------- GEMM: C = A * W^T + bias (A: MxK, W: NxK, bf16, fp32 acc) --------
template <int OUTF32>
__global__ __launch_bounds__(256) void gemm_bt(
    const unsigned short* __restrict__ A0, const unsigned short* __restrict__ A1,
    const unsigned short* __restrict__ A2,
    const unsigned short* __restrict__ W0, const unsigned short* __restrict__ W1,
    const unsigned short* __restrict__ W2,
    const float* __restrict__ b0, const float* __restrict__ b1, const float* __restrict__ b2,
    void* __restrict__ C0, void* __restrict__ C1, void* __restrict__ C2,
    float s0, float s1, float s2, int M, int N, int K) {
  const int z = blockIdx.z;
  const unsigned short* A = (z == 0) ? A0 : ((z == 1) ? A1 : A2);
  const unsigned short* W = (z == 0) ? W0 : ((z == 1) ? W1 : W2);
  const float* bias = (z == 0) ? b0 : ((z == 1) ? b1 : b2);
  void* Cout = (z == 0) ? C0 : ((z == 1) ? C1 : C2);
  const float scale = (z == 0) ? s0 : ((z == 1) ? s1 : s2);

  __shared__ unsigned short As[128 * 40];
  __shared__ unsigned short Bs[128 * 40];

  const int tid = threadIdx.x;
  const int lane = tid & 63;
  const int wid = tid >> 6;
  const int bm = blockIdx.x, bn = blockIdx.y;
  const int wm = (wid >> 1) * 64, wn = (wid & 1) * 64;

  f32x4 acc[4][4];
#pragma unroll
  for (int i = 0; i < 4; i++)
#pragma unroll
    for (int j = 0; j < 4; j++) acc[i][j] = (f32x4){0.f, 0.f, 0.f, 0.f};

  const int r0 = tid >> 2;
  const int c0 = (tid & 3) * 8;
  const unsigned short* Ag = A + (size_t)(bm * 128 + r0) * K + c0;
  const unsigned short* Bg = W + (size_t)(bn * 128 + r0) * K + c0;

  short8 va[2], vb[2];
#pragma unroll
  for (int j = 0; j < 2; j++) {
    va[j] = *(const short8*)(Ag + (size_t)(j * 64) * K);
    vb[j] = *(const short8*)(Bg + (size_t)(j * 64) * K);
  }

  for (int k0 = 0; k0 < K; k0 += 32) {
#pragma unroll
    for (int j = 0; j < 2; j++) {
      *(short8*)&As[(j * 64 + r0) * 40 + c0] = va[j];
      *(short8*)&Bs[(j * 64 + r0) * 40 + c0] = vb[j];
    }
    __syncthreads();
    if (k0 + 32 < K) {
#pragma unroll
      for (int j = 0; j < 2; j++) {
        va[j] = *(const short8*)(Ag + (size_t)(j * 64) * K + k0 + 32);
        vb[j] = *(const short8*)(Bg + (size_t)(j * 64) * K + k0 + 32);
      }
    }
    short8 af[4], bf[4];
#pragma unroll
    for (int i = 0; i < 4; i++)
      af[i] = *(const short8*)&As[(wm + i * 16 + (lane & 15)) * 40 + (lane >> 4) * 8];
#pragma unroll
    for (int i = 0; i < 4; i++)
      bf[i] = *(const short8*)&Bs[(wn + i * 16 + (lane & 15)) * 40 + (lane >> 4) * 8];
#pragma unroll
    for (int i = 0; i < 4; i++)
#pragma unroll
      for (int j = 0; j < 4; j++) acc[i][j] = MFMA16(af[i], bf[j], acc[i][j]);
    __syncthreads();
  }

  const int crow = bm * 128 + wm + (lane >> 4) * 4;
#pragma unroll
  for (int j = 0; j < 4; j++) {
    const int col = bn * 128 + wn + j * 16 + (lane & 15);
    const float bv = bias[col];
#pragma unroll
    for (int i = 0; i < 4; i++) {
#pragma unroll
      for (int r = 0; r < 4; r++) {
        float vvv = (acc[i][j][r] + bv) * scale;
        const size_t off = (size_t)(crow + i * 16 + r) * N + col;
        if (OUTF32)
          ((float*)Cout)[off] = vvv;
        else
          ((unsigned short*)Cout)[off] = f2bf(vvv);
      }
    }
  }
}

// ---------------- V transpose: (B,L,D) bf16 -> (B,D,L) bf16 ----------------
__global__ __launch_bounds__(256) void transpose_v(const unsigned short* __restrict__ Vp,
                                                   unsigned short* __restrict__ Vt) {
  __shared__ unsigned short T[64][72];
  const int tid = threadIdx.x;
  const int l0 = blockIdx.x * 64;
  const int d0 = blockIdx.y * 64;
  const int b = blockIdx.z;
  const int r = tid >> 2, c = (tid & 3) * 16;
  const unsigned short* src =
      Vp + (size_t)b * LSEQ * DMOD + (size_t)(l0 + r) * DMOD + d0 + c;
  *(short8*)&T[r][c] = *(const short8*)(src);
  *(short8*)&T[r][c + 8] = *(const short8*)(src + 8);
  __syncthreads();
  unsigned short tmp[16];
#pragma unroll
  for (int x = 0; x < 16; x++) tmp[x] = T[c + x][r];
  unsigned short* dst = Vt + (size_t)b * DMOD * LSEQ + (size_t)(d0 + r) * LSEQ + l0 + c;
  *(short8*)(dst) = *(short8*)&tmp[0];
  *(short8*)(dst + 8) = *(short8*)&tmp[8];
}

// ---------------- fused attention (v4) ----------------
// grid: (L/128, B*H), 256 thr, 3 blocks/CU (51 KB LDS, launch_bounds(256,3)).
// 2x2 q-split x k-split waves. Ks XOR-swizzled [128][64] linear. V read direct
// from global (L2-resident, no LDS stage). Per-tile uniform all-ones-mask fast
// path via precomputed flags (slow path = full mask semantics).
__global__ __launch_bounds__(256, 3) void attn_kernel(
    const unsigned short* __restrict__ Qp, const unsigned short* __restrict__ Kp,
    const unsigned short* __restrict__ Vt, const int* __restrict__ mask,
    const int* __restrict__ flags, float* __restrict__ attn_out,
    unsigned short* __restrict__ ctx) {
  __shared__ unsigned short Ks[128 * 64];   // 16 KB, XOR-swizzled
  __shared__ unsigned short Ps[4][64][68];  // 34 KB
  __shared__ float denbuf[2][128];          // 1 KB

  const int tid = threadIdx.x, lane = tid & 63, wid = tid >> 6;
  const int kw = wid & 1, qw = wid >> 1;
  const int l15 = lane & 15, lg = lane >> 4;
  const int qt = blockIdx.x;
  const int q0 = qt * 128;
  const int bh = blockIdx.y;
  const int b = bh >> 4, h = bh & 15;

  const unsigned short* Qh = Qp + (size_t)b * LSEQ * DMOD + h * HDSZ;
  const unsigned short* Kh = Kp + (size_t)b * LSEQ * DMOD + h * HDSZ;
  const unsigned short* Vh = Vt + (size_t)b * DMOD * LSEQ + (size_t)h * HDSZ * LSEQ;
  const int* mb = mask + (size_t)b * LSEQ * LSEQ;
  const int* frow = flags + (b * 16 + qt) * 16;
  float* ah = attn_out + (size_t)bh * LSEQ * LSEQ;

  const int wq0 = q0 + qw * 64;
  const int wk0 = kw * 64;

  // Q fragments (B-operand): lane holds Q[wq0+fq*16+l15][ks*32+lg*8 ..+7]
  short8 qf[4][2];
#pragma unroll
  for (int fq = 0; fq < 4; fq++)
#pragma unroll
    for (int ks = 0; ks < 2; ks++)
      qf[fq][ks] = *(const short8*)(Qh + (size_t)(wq0 + fq * 16 + l15) * DMOD +
                                    ks * 32 + lg * 8);

  // K staging: thread -> row sr, 64B half (tid&1), 4 chunks of 16B
  const int sr = tid >> 1;
  const unsigned short* Kst = Kh + (size_t)sr * DMOD + (tid & 1) * 32;
  const int swz_w = (sr & 7) << 4;  // write-side XOR (byte space)
  // read-side helper index (ushort): row*64 + ((ks*64+lg*16) ^ ((row&7)<<4))/2

  // ---------------- sweep 1: denominators ----------------
  float den[4] = {0.f, 0.f, 0.f, 0.f};
  short8 ka[4];
#pragma unroll
  for (int j = 0; j < 4; j++) ka[j] = *(const short8*)(Kst + j * 8);

  for (int kt = 0; kt < LSEQ / 128; ++kt) {
    __syncthreads();
#pragma unroll
    for (int j = 0; j < 4; j++)
      *(short8*)&Ks[sr * 64 + (((((tid & 1) * 64) + j * 16) ^ swz_w) >> 1)] = ka[j];
    __syncthreads();
    if (kt + 1 < LSEQ / 128) {
#pragma unroll
      for (int j = 0; j < 4; j++)
        ka[j] = *(const short8*)(Kst + (size_t)(kt + 1) * 128 * DMOD + j * 8);
    }
    const bool fast = frow[kt] != 0;
    if (fast) {
#pragma unroll
      for (int fn = 0; fn < 4; fn++) {
        const int krow = wk0 + fn * 16 + l15;
        const int rb = krow * 64, rx = (krow & 7) << 4;
        short8 kf0 = *(const short8*)&Ks[rb + (((lg * 16) ^ rx) >> 1)];
        short8 kf1 = *(const short8*)&Ks[rb + (((64 + lg * 16) ^ rx) >> 1)];
#pragma unroll
        for (int fq = 0; fq < 4; fq++) {
          f32x4 s = (f32x4){0.f, 0.f, 0.f, 0.f};
          s = MFMA16(kf0, qf[fq][0], s);
          s = MFMA16(kf1, qf[fq][1], s);
          den[fq] += __expf(s[0]) + __expf(s[1]) + __expf(s[2]) + __expf(s[3]);
        }
      }
    } else {
      const int k0 = kt * 128;
#pragma unroll
      for (int fn = 0; fn < 4; fn++) {
        const int krow = wk0 + fn * 16 + l15;
        const int rb = krow * 64, rx = (krow & 7) << 4;
        short8 kf0 = *(const short8*)&Ks[rb + (((lg * 16) ^ rx) >> 1)];
        short8 kf1 = *(const short8*)&Ks[rb + (((64 + lg * 16) ^ rx) >> 1)];
#pragma unroll
        for (int fq = 0; fq < 4; fq++) {
          const int qrow = wq0 + fq * 16 + l15;
          f32x4 s = (f32x4){0.f, 0.f, 0.f, 0.f};
          s = MFMA16(kf0, qf[fq][0], s);
          s = MFMA16(kf1, qf[fq][1], s);
          i32x4 m4 = *(const i32x4*)(mb + (size_t)qrow * LSEQ + k0 + wk0 + fn * 16 + lg * 4);
          den[fq] += (m4[0] != 0) ? __expf(s[0]) : 0.f;
          den[fq] += (m4[1] != 0) ? __expf(s[1]) : 0.f;
          den[fq] += (m4[2] != 0) ? __expf(s[2]) : 0.f;
          den[fq] += (m4[3] != 0) ? __expf(s[3]) : 0.f;
        }
      }
    }
  }
#pragma unroll
  for (int fq = 0; fq < 4; fq++) {
    den[fq] += __shfl_xor(den[fq], 16);
    den[fq] += __shfl_xor(den[fq], 32);
  }
  if (lg == 0) {
#pragma unroll
    for (int fq = 0; fq < 4; fq++) denbuf[kw][qw * 64 + fq * 16 + l15] = den[fq];
  }
  __syncthreads();
  float inv[4];
#pragma unroll
  for (int fq = 0; fq < 4; fq++) {
    const int ql = qw * 64 + fq * 16 + l15;
    inv[fq] = 1.0f / (denbuf[0][ql] + denbuf[1][ql]);
  }

  // ---------------- sweep 2: attn write + PV ----------------
  f32x4 oacc[4][4];
#pragma unroll
  for (int fq = 0; fq < 4; fq++)
#pragma unroll
    for (int fd = 0; fd < 4; fd++) oacc[fq][fd] = (f32x4){0.f, 0.f, 0.f, 0.f};

#pragma unroll
  for (int j = 0; j < 4; j++) ka[j] = *(const short8*)(Kst + j * 8);

  const unsigned short* Vbase = Vh + (size_t)l15 * LSEQ + wk0 + lg * 8;

  for (int kt = 0; kt < LSEQ / 128; ++kt) {
    const int k0 = kt * 128;
    __syncthreads();
#pragma unroll
    for (int j = 0; j < 4; j++)
      *(short8*)&Ks[sr * 64 + (((((tid & 1) * 64) + j * 16) ^ swz_w) >> 1)] = ka[j];
    __syncthreads();
    if (kt + 1 < LSEQ / 128) {
#pragma unroll
      for (int j = 0; j < 4; j++)
        ka[j] = *(const short8*)(Kst + (size_t)(kt + 1) * 128 * DMOD + j * 8);
    }
    // V fragments direct from global (L2-resident); issued early to hide latency
    short8 vf[4][2];
#pragma unroll
    for (int fd = 0; fd < 4; fd++)
#pragma unroll
      for (int ks = 0; ks < 2; ks++)
        vf[fd][ks] = *(const short8*)(Vbase + (size_t)(fd * 16) * LSEQ + k0 + ks * 32);

    const bool fast = frow[kt] != 0;
    if (fast) {
#pragma unroll
      for (int fn = 0; fn < 4; fn++) {
        const int krow = wk0 + fn * 16 + l15;
        const int rb = krow * 64, rx = (krow & 7) << 4;
        short8 kf0 = *(const short8*)&Ks[rb + (((lg * 16) ^ rx) >> 1)];
        short8 kf1 = *(const short8*)&Ks[rb + (((64 + lg * 16) ^ rx) >> 1)];
#pragma unroll
        for (int fq = 0; fq < 4; fq++) {
          const int qrow = wq0 + fq * 16 + l15;
          f32x4 s = (f32x4){0.f, 0.f, 0.f, 0.f};
          s = MFMA16(kf0, qf[fq][0], s);
          s = MFMA16(kf1, qf[fq][1], s);
          f32x4 a;
          a[0] = __expf(s[0]) * inv[fq];
          a[1] = __expf(s[1]) * inv[fq];
          a[2] = __expf(s[2]) * inv[fq];
          a[3] = __expf(s[3]) * inv[fq];
          *(f32x4*)(ah + (size_t)qrow * LSEQ + k0 + wk0 + fn * 16 + lg * 4) = a;
          u16x4 pk;
          pk[0] = f2bf(a[0]); pk[1] = f2bf(a[1]); pk[2] = f2bf(a[2]); pk[3] = f2bf(a[3]);
          *(u16x4*)&Ps[wid][fq * 16 + l15][fn * 16 + lg * 4] = pk;
        }
      }
    } else {
#pragma unroll
      for (int fn = 0; fn < 4; fn++) {
        const int krow = wk0 + fn * 16 + l15;
        const int rb = krow * 64, rx = (krow & 7) << 4;
        short8 kf0 = *(const short8*)&Ks[rb + (((lg * 16) ^ rx) >> 1)];
        short8 kf1 = *(const short8*)&Ks[rb + (((64 + lg * 16) ^ rx) >> 1)];
#pragma unroll
        for (int fq = 0; fq < 4; fq++) {
          const int qrow = wq0 + fq * 16 + l15;
          f32x4 s = (f32x4){0.f, 0.f, 0.f, 0.f};
          s = MFMA16(kf0, qf[fq][0], s);
          s = MFMA16(kf1, qf[fq][1], s);
          i32x4 m4 = *(const i32x4*)(mb + (size_t)qrow * LSEQ + k0 + wk0 + fn * 16 + lg * 4);
          f32x4 a;
          a[0] = (m4[0] != 0) ? __expf(s[0]) * inv[fq] : 0.f;
          a[1] = (m4[1] != 0) ? __expf(s[1]) * inv[fq] : 0.f;
          a[2] = (m4[2] != 0) ? __expf(s[2]) * inv[fq] : 0.f;
          a[3] = (m4[3] != 0) ? __expf(s[3]) * inv[fq] : 0.f;
          *(f32x4*)(ah + (size_t)qrow * LSEQ + k0 + wk0 + fn * 16 + lg * 4) = a;
          u16x4 pk;
          pk[0] = f2bf(a[0]); pk[1] = f2bf(a[1]); pk[2] = f2bf(a[2]); pk[3] = f2bf(a[3]);
          *(u16x4*)&Ps[wid][fq * 16 + l15][fn * 16 + lg * 4] = pk;
        }
      }
    }
    // PV: A = Ps rows (wave-private), B = V^T rows (registers)
    short8 pa2[4][2];
#pragma unroll
    for (int fq = 0; fq < 4; fq++)
#pragma unroll
      for (int ks = 0; ks < 2; ks++)
        pa2[fq][ks] = *(const short8*)&Ps[wid][fq * 16 + l15][ks * 32 + lg * 8];
#pragma unroll
    for (int fd = 0; fd < 4; fd++) {
#pragma unroll
      for (int fq = 0; fq < 4; fq++) {
        oacc[fq][fd] = MFMA16(pa2[fq][0], vf[fd][0], oacc[fq][fd]);
        oacc[fq][fd] = MFMA16(pa2[fq][1], vf[fd][1], oacc[fq][fd]);
      }
    }
  }

  // ---------------- k-split reduction + ctx store ----------------
  __syncthreads();  // Ps dead; reuse as fp32 reduction buffer (stride 65)
  float* red = (float*)&Ps[qw * 2][0][0];  // 2 buffers = 17408 B >= 64*65*4
  if (kw == 1) {
#pragma unroll
    for (int fq = 0; fq < 4; fq++)
#pragma unroll
      for (int fd = 0; fd < 4; fd++)
#pragma unroll
        for (int r = 0; r < 4; r++)
          red[(fq * 16 + lg * 4 + r) * 65 + fd * 16 + l15] = oacc[fq][fd][r];
  }
  __syncthreads();
  if (kw == 0) {
    unsigned short* ch = ctx + (size_t)b * LSEQ * DMOD + h * HDSZ;
#pragma unroll
    for (int fq = 0; fq < 4; fq++)
#pragma unroll
      for (int fd = 0; fd < 4; fd++)
#pragma unroll
        for (int r = 0; r < 4; r++) {
          const int qr = wq0 + fq * 16 + lg * 4 + r;
          const float o = oacc[fq][fd][r] + red[(fq * 16 + lg * 4 + r) * 65 + fd * 16 + l15];
          ch[(size_t)qr * DMOD + fd * 16 + l15] = f2bf(o);
        }
  }
}

// ---------------- launcher ----------------
extern "C" void kernel_launch(void* const* d_in, const int* in_sizes, int n_in,
                              void* d_out, int out_size, void* d_ws, size_t ws_size,
                              hipStream_t stream) {
  const float* q = (const float*)d_in[0];
  const float* k = (const float*)d_in[1];
  const float* v = (const float*)d_in[2];
  const int* mask = (const int*)d_in[3];
  const float* Wq = (const float*)d_in[4];
  const float* bq = (const float*)d_in[5];
  const float* Wk = (const float*)d_in[6];
  const float* bk = (const float*)d_in[7];
  const float* Wv = (const float*)d_in[8];
  const float* bv = (const float*)d_in[9];
  const float* Wo = (const float*)d_in[10];
  const float* bo = (const float*)d_in[11];

  float* out = (float*)d_out;
  float* attn = out + (size_t)BSZ * LSEQ * DMOD;

  const size_t NQKV = (size_t)BSZ * LSEQ * DMOD;
  const size_t NW = (size_t)DMOD * DMOD;

  // dead-before-attention scratch lives inside the attn output region
  unsigned short* qb = (unsigned short*)attn;
  unsigned short* kb = qb + NQKV;
  unsigned short* vb = kb + NQKV;
  unsigned short* Wqb = vb + NQKV;
  unsigned short* Wkb = Wqb + NW;
  unsigned short* Wvb = Wkb + NW;
  unsigned short* Vp = Wvb + NW;

  // flags live in the (not-yet-written) out region: consumed by attn,
  // overwritten by the final output projection.
  int* flags = (int*)out;  // 512 ints

  // survives attention -> d_ws
  unsigned short* Qp = (unsigned short*)d_ws;
  unsigned short* Kp = Qp + NQKV;
  unsigned short* Vt = Kp + NQKV;
  unsigned short* ctx = Vt + NQKV;
  unsigned short* Wob = ctx + NQKV;

  cvt_bf16<<<dim3(NQKV / 4 / 256), 256, 0, stream>>>(q, qb, (int)NQKV);
  cvt_bf16<<<dim3(NQKV / 4 / 256), 256, 0, stream>>>(k, kb, (int)NQKV);
  cvt_bf16<<<dim3(NQKV / 4 / 256), 256, 0, stream>>>(v, vb, (int)NQKV);
  cvt_bf16<<<dim3(NW / 4 / 256), 256, 0, stream>>>(Wq, Wqb, (int)NW);
  cvt_bf16<<<dim3(NW / 4 / 256), 256, 0, stream>>>(Wk, Wkb, (int)NW);
  cvt_bf16<<<dim3(NW / 4 / 256), 256, 0, stream>>>(Wv, Wvb, (int)NW);
  cvt_bf16<<<dim3(NW / 4 / 256), 256, 0, stream>>>(Wo, Wob, (int)NW);

  mask_check<<<dim3(16, 16, BSZ), 256, 0, stream>>>(mask, flags);

  gemm_bt<0><<<dim3(32, 8, 3), 256, 0, stream>>>(
      qb, kb, vb, Wqb, Wkb, Wvb, bq, bk, bv, (void*)Qp, (void*)Kp, (void*)Vp,
      0.125f, 1.0f, 1.0f, BSZ * LSEQ, DMOD, DMOD);

  transpose_v<<<dim3(LSEQ / 64, DMOD / 64, BSZ), 256, 0, stream>>>(Vp, Vt);

  attn_kernel<<<dim3(LSEQ / 128, BSZ * NH), 256, 0, stream>>>(Qp, Kp, Vt, mask, flags,
                                                              attn, ctx);

  gemm_bt<1><<<dim3(32, 8, 1), 256, 0, stream>>>(
      ctx, ctx, ctx, Wob, Wob, Wob, bo, bo, bo, (void*)out, (void*)out, (void*)out,
      1.0f, 1.0f, 1.0f, BSZ * LSEQ, DMOD, DMOD);
}

// Round 5
// 304.225 us; speedup vs baseline: 1.3724x; 1.3724x over previous
//
#include <hip/hip_runtime.h>
#include <stdint.h>

#define BSZ 2
#define LSEQ 2048
#define DMOD 1024
#define NH 16
#define HDSZ 64

typedef __attribute__((ext_vector_type(8))) short short8;
typedef __attribute__((ext_vector_type(4))) float f32x4;
typedef __attribute__((ext_vector_type(4))) unsigned short u16x4;
typedef __attribute__((ext_vector_type(4))) int i32x4;

#define MFMA16(a, b, c) __builtin_amdgcn_mfma_f32_16x16x32_bf16((a), (b), (c), 0, 0, 0)

__device__ __forceinline__ unsigned short f2bf(float f) {
  union { float f; unsigned u; } x; x.f = f;
  unsigned u = x.u + 0x7fffu + ((x.u >> 16) & 1u);
  return (unsigned short)(u >> 16);
}

// ---------------- fp32 -> bf16 conversion ----------------
__global__ __launch_bounds__(256) void cvt_bf16(const float* __restrict__ in,
                                                unsigned short* __restrict__ out, int n) {
  int i = (blockIdx.x * 256 + threadIdx.x) * 4;
  if (i >= n) return;
  f32x4 v = *(const f32x4*)(in + i);
  u16x4 o;
  o[0] = f2bf(v[0]); o[1] = f2bf(v[1]); o[2] = f2bf(v[2]); o[3] = f2bf(v[3]);
  *(u16x4*)(out + i) = o;
}

// ---------------- mask check: flags[b][qt][kt] = all-nonzero over 128x128 tile ----
__global__ __launch_bounds__(256) void mask_check(const int* __restrict__ mask,
                                                  int* __restrict__ flags) {
  const int kt = blockIdx.x, qt = blockIdx.y, b = blockIdx.z;
  const int tid = threadIdx.x;
  const int r = tid >> 1, c = (tid & 1) * 64;
  const int* mr = mask + (size_t)b * LSEQ * LSEQ + (size_t)(qt * 128 + r) * LSEQ + kt * 128 + c;
  int ok = 1;
#pragma unroll
  for (int j = 0; j < 16; j++) {
    i32x4 v = *(const i32x4*)(mr + j * 4);
    ok &= (v[0] != 0) & (v[1] != 0) & (v[2] != 0) & (v[3] != 0);
  }
  __shared__ int red[4];
  unsigned long long vote = __ballot(ok);
  if ((tid & 63) == 0) red[tid >> 6] = (vote == ~0ull) ? 1 : 0;
  __syncthreads();
  if (tid == 0) flags[(b * 16 + qt) * 16 + kt] = red[0] & red[1] & red[2] & red[3];
}

// ---------------- GEMM: C = A * W^T + bias (A: MxK, W: NxK, bf16, fp32 acc) --------
template <int OUTF32>
__global__ __launch_bounds__(256) void gemm_bt(
    const unsigned short* __restrict__ A0, const unsigned short* __restrict__ A1,
    const unsigned short* __restrict__ A2,
    const unsigned short* __restrict__ W0, const unsigned short* __restrict__ W1,
    const unsigned short* __restrict__ W2,
    const float* __restrict__ b0, const float* __restrict__ b1, const float* __restrict__ b2,
    void* __restrict__ C0, void* __restrict__ C1, void* __restrict__ C2,
    float s0, float s1, float s2, int M, int N, int K) {
  const int z = blockIdx.z;
  const unsigned short* A = (z == 0) ? A0 : ((z == 1) ? A1 : A2);
  const unsigned short* W = (z == 0) ? W0 : ((z == 1) ? W1 : W2);
  const float* bias = (z == 0) ? b0 : ((z == 1) ? b1 : b2);
  void* Cout = (z == 0) ? C0 : ((z == 1) ? C1 : C2);
  const float scale = (z == 0) ? s0 : ((z == 1) ? s1 : s2);

  __shared__ unsigned short As[128 * 40];
  __shared__ unsigned short Bs[128 * 40];

  const int tid = threadIdx.x;
  const int lane = tid & 63;
  const int wid = tid >> 6;
  const int bm = blockIdx.x, bn = blockIdx.y;
  const int wm = (wid >> 1) * 64, wn = (wid & 1) * 64;

  f32x4 acc[4][4];
#pragma unroll
  for (int i = 0; i < 4; i++)
#pragma unroll
    for (int j = 0; j < 4; j++) acc[i][j] = (f32x4){0.f, 0.f, 0.f, 0.f};

  const int r0 = tid >> 2;
  const int c0 = (tid & 3) * 8;
  const unsigned short* Ag = A + (size_t)(bm * 128 + r0) * K + c0;
  const unsigned short* Bg = W + (size_t)(bn * 128 + r0) * K + c0;

  short8 va[2], vb[2];
#pragma unroll
  for (int j = 0; j < 2; j++) {
    va[j] = *(const short8*)(Ag + (size_t)(j * 64) * K);
    vb[j] = *(const short8*)(Bg + (size_t)(j * 64) * K);
  }

  for (int k0 = 0; k0 < K; k0 += 32) {
#pragma unroll
    for (int j = 0; j < 2; j++) {
      *(short8*)&As[(j * 64 + r0) * 40 + c0] = va[j];
      *(short8*)&Bs[(j * 64 + r0) * 40 + c0] = vb[j];
    }
    __syncthreads();
    if (k0 + 32 < K) {
#pragma unroll
      for (int j = 0; j < 2; j++) {
        va[j] = *(const short8*)(Ag + (size_t)(j * 64) * K + k0 + 32);
        vb[j] = *(const short8*)(Bg + (size_t)(j * 64) * K + k0 + 32);
      }
    }
    short8 af[4], bf[4];
#pragma unroll
    for (int i = 0; i < 4; i++)
      af[i] = *(const short8*)&As[(wm + i * 16 + (lane & 15)) * 40 + (lane >> 4) * 8];
#pragma unroll
    for (int i = 0; i < 4; i++)
      bf[i] = *(const short8*)&Bs[(wn + i * 16 + (lane & 15)) * 40 + (lane >> 4) * 8];
#pragma unroll
    for (int i = 0; i < 4; i++)
#pragma unroll
      for (int j = 0; j < 4; j++) acc[i][j] = MFMA16(af[i], bf[j], acc[i][j]);
    __syncthreads();
  }

  const int crow = bm * 128 + wm + (lane >> 4) * 4;
#pragma unroll
  for (int j = 0; j < 4; j++) {
    const int col = bn * 128 + wn + j * 16 + (lane & 15);
    const float bv = bias[col];
#pragma unroll
    for (int i = 0; i < 4; i++) {
#pragma unroll
      for (int r = 0; r < 4; r++) {
        float vvv = (acc[i][j][r] + bv) * scale;
        const size_t off = (size_t)(crow + i * 16 + r) * N + col;
        if (OUTF32)
          ((float*)Cout)[off] = vvv;
        else
          ((unsigned short*)Cout)[off] = f2bf(vvv);
      }
    }
  }
}

// ---------------- V transpose: (B,L,D) bf16 -> (B,D,L) bf16 ----------------
__global__ __launch_bounds__(256) void transpose_v(const unsigned short* __restrict__ Vp,
                                                   unsigned short* __restrict__ Vt) {
  __shared__ unsigned short T[64][72];
  const int tid = threadIdx.x;
  const int l0 = blockIdx.x * 64;
  const int d0 = blockIdx.y * 64;
  const int b = blockIdx.z;
  const int r = tid >> 2, c = (tid & 3) * 16;
  const unsigned short* src =
      Vp + (size_t)b * LSEQ * DMOD + (size_t)(l0 + r) * DMOD + d0 + c;
  *(short8*)&T[r][c] = *(const short8*)(src);
  *(short8*)&T[r][c + 8] = *(const short8*)(src + 8);
  __syncthreads();
  unsigned short tmp[16];
#pragma unroll
  for (int x = 0; x < 16; x++) tmp[x] = T[c + x][r];
  unsigned short* dst = Vt + (size_t)b * DMOD * LSEQ + (size_t)(d0 + r) * LSEQ + l0 + c;
  *(short8*)(dst) = *(short8*)&tmp[0];
  *(short8*)(dst + 8) = *(short8*)&tmp[8];
}

// ---------------- fused attention (v5) ----------------
// v4 minus the __launch_bounds__(256,3) VGPR cap (spill suspect), plus
// XCD-aware block remap: all 16 q-tiles of one head on the same XCD so its
// L2 holds that head's K/V. 2x2 q-split x k-split waves; Ks XOR-swizzled
// [128][64]; V direct from global (L2-resident); per-tile all-ones-mask
// uniform fast path (slow path = full mask semantics).
__global__ __launch_bounds__(256) void attn_kernel(
    const unsigned short* __restrict__ Qp, const unsigned short* __restrict__ Kp,
    const unsigned short* __restrict__ Vt, const int* __restrict__ mask,
    const int* __restrict__ flags, float* __restrict__ attn_out,
    unsigned short* __restrict__ ctx) {
  __shared__ unsigned short Ks[128 * 64];   // 16 KB, XOR-swizzled
  __shared__ unsigned short Ps[4][64][68];  // 34 KB
  __shared__ float denbuf[2][128];          // 1 KB

  const int tid = threadIdx.x, lane = tid & 63, wid = tid >> 6;
  const int kw = wid & 1, qw = wid >> 1;
  const int l15 = lane & 15, lg = lane >> 4;

  // XCD-aware remap: wgid%8 = XCD (round-robin dispatch); give XCD c heads
  // {4c..4c+3}, all 16 q-tiles of a head on one XCD (K/V L2-resident).
  const int wgid = blockIdx.x + gridDim.x * blockIdx.y;  // 0..511
  const int jj = wgid >> 3;                              // 0..63
  const int bh = (wgid & 7) * 4 + (jj >> 4);             // 0..31
  const int qt = jj & 15;                                // 0..15
  const int q0 = qt * 128;
  const int b = bh >> 4, h = bh & 15;

  const unsigned short* Qh = Qp + (size_t)b * LSEQ * DMOD + h * HDSZ;
  const unsigned short* Kh = Kp + (size_t)b * LSEQ * DMOD + h * HDSZ;
  const unsigned short* Vh = Vt + (size_t)b * DMOD * LSEQ + (size_t)h * HDSZ * LSEQ;
  const int* mb = mask + (size_t)b * LSEQ * LSEQ;
  const int* frow = flags + (b * 16 + qt) * 16;
  float* ah = attn_out + (size_t)bh * LSEQ * LSEQ;

  const int wq0 = q0 + qw * 64;
  const int wk0 = kw * 64;

  // Q fragments (B-operand): lane holds Q[wq0+fq*16+l15][ks*32+lg*8 ..+7]
  short8 qf[4][2];
#pragma unroll
  for (int fq = 0; fq < 4; fq++)
#pragma unroll
    for (int ks = 0; ks < 2; ks++)
      qf[fq][ks] = *(const short8*)(Qh + (size_t)(wq0 + fq * 16 + l15) * DMOD +
                                    ks * 32 + lg * 8);

  // K staging: thread -> row sr, 64B half (tid&1), 4 chunks of 16B
  const int sr = tid >> 1;
  const unsigned short* Kst = Kh + (size_t)sr * DMOD + (tid & 1) * 32;
  const int swz_w = (sr & 7) << 4;  // write-side XOR (byte space)

  // ---------------- sweep 1: denominators ----------------
  float den[4] = {0.f, 0.f, 0.f, 0.f};
  short8 ka[4];
#pragma unroll
  for (int j = 0; j < 4; j++) ka[j] = *(const short8*)(Kst + j * 8);

  for (int kt = 0; kt < LSEQ / 128; ++kt) {
    __syncthreads();
#pragma unroll
    for (int j = 0; j < 4; j++)
      *(short8*)&Ks[sr * 64 + (((((tid & 1) * 64) + j * 16) ^ swz_w) >> 1)] = ka[j];
    __syncthreads();
    if (kt + 1 < LSEQ / 128) {
#pragma unroll
      for (int j = 0; j < 4; j++)
        ka[j] = *(const short8*)(Kst + (size_t)(kt + 1) * 128 * DMOD + j * 8);
    }
    const bool fast = frow[kt] != 0;
    if (fast) {
#pragma unroll
      for (int fn = 0; fn < 4; fn++) {
        const int krow = wk0 + fn * 16 + l15;
        const int rb = krow * 64, rx = (krow & 7) << 4;
        short8 kf0 = *(const short8*)&Ks[rb + (((lg * 16) ^ rx) >> 1)];
        short8 kf1 = *(const short8*)&Ks[rb + (((64 + lg * 16) ^ rx) >> 1)];
#pragma unroll
        for (int fq = 0; fq < 4; fq++) {
          f32x4 s = (f32x4){0.f, 0.f, 0.f, 0.f};
          s = MFMA16(kf0, qf[fq][0], s);
          s = MFMA16(kf1, qf[fq][1], s);
          den[fq] += __expf(s[0]) + __expf(s[1]) + __expf(s[2]) + __expf(s[3]);
        }
      }
    } else {
      const int k0 = kt * 128;
#pragma unroll
      for (int fn = 0; fn < 4; fn++) {
        const int krow = wk0 + fn * 16 + l15;
        const int rb = krow * 64, rx = (krow & 7) << 4;
        short8 kf0 = *(const short8*)&Ks[rb + (((lg * 16) ^ rx) >> 1)];
        short8 kf1 = *(const short8*)&Ks[rb + (((64 + lg * 16) ^ rx) >> 1)];
#pragma unroll
        for (int fq = 0; fq < 4; fq++) {
          const int qrow = wq0 + fq * 16 + l15;
          f32x4 s = (f32x4){0.f, 0.f, 0.f, 0.f};
          s = MFMA16(kf0, qf[fq][0], s);
          s = MFMA16(kf1, qf[fq][1], s);
          i32x4 m4 = *(const i32x4*)(mb + (size_t)qrow * LSEQ + k0 + wk0 + fn * 16 + lg * 4);
          den[fq] += (m4[0] != 0) ? __expf(s[0]) : 0.f;
          den[fq] += (m4[1] != 0) ? __expf(s[1]) : 0.f;
          den[fq] += (m4[2] != 0) ? __expf(s[2]) : 0.f;
          den[fq] += (m4[3] != 0) ? __expf(s[3]) : 0.f;
        }
      }
    }
  }
#pragma unroll
  for (int fq = 0; fq < 4; fq++) {
    den[fq] += __shfl_xor(den[fq], 16);
    den[fq] += __shfl_xor(den[fq], 32);
  }
  if (lg == 0) {
#pragma unroll
    for (int fq = 0; fq < 4; fq++) denbuf[kw][qw * 64 + fq * 16 + l15] = den[fq];
  }
  __syncthreads();
  float inv[4];
#pragma unroll
  for (int fq = 0; fq < 4; fq++) {
    const int ql = qw * 64 + fq * 16 + l15;
    inv[fq] = 1.0f / (denbuf[0][ql] + denbuf[1][ql]);
  }

  // ---------------- sweep 2: attn write + PV ----------------
  f32x4 oacc[4][4];
#pragma unroll
  for (int fq = 0; fq < 4; fq++)
#pragma unroll
    for (int fd = 0; fd < 4; fd++) oacc[fq][fd] = (f32x4){0.f, 0.f, 0.f, 0.f};

#pragma unroll
  for (int j = 0; j < 4; j++) ka[j] = *(const short8*)(Kst + j * 8);

  const unsigned short* Vbase = Vh + (size_t)l15 * LSEQ + wk0 + lg * 8;

  for (int kt = 0; kt < LSEQ / 128; ++kt) {
    const int k0 = kt * 128;
    __syncthreads();
#pragma unroll
    for (int j = 0; j < 4; j++)
      *(short8*)&Ks[sr * 64 + (((((tid & 1) * 64) + j * 16) ^ swz_w) >> 1)] = ka[j];
    __syncthreads();
    // V fragments direct from global (L2-resident); issued early, used at PV
    short8 vf[4][2];
#pragma unroll
    for (int fd = 0; fd < 4; fd++)
#pragma unroll
      for (int ks = 0; ks < 2; ks++)
        vf[fd][ks] = *(const short8*)(Vbase + (size_t)(fd * 16) * LSEQ + k0 + ks * 32);
    if (kt + 1 < LSEQ / 128) {
#pragma unroll
      for (int j = 0; j < 4; j++)
        ka[j] = *(const short8*)(Kst + (size_t)(kt + 1) * 128 * DMOD + j * 8);
    }

    const bool fast = frow[kt] != 0;
    if (fast) {
#pragma unroll
      for (int fn = 0; fn < 4; fn++) {
        const int krow = wk0 + fn * 16 + l15;
        const int rb = krow * 64, rx = (krow & 7) << 4;
        short8 kf0 = *(const short8*)&Ks[rb + (((lg * 16) ^ rx) >> 1)];
        short8 kf1 = *(const short8*)&Ks[rb + (((64 + lg * 16) ^ rx) >> 1)];
#pragma unroll
        for (int fq = 0; fq < 4; fq++) {
          const int qrow = wq0 + fq * 16 + l15;
          f32x4 s = (f32x4){0.f, 0.f, 0.f, 0.f};
          s = MFMA16(kf0, qf[fq][0], s);
          s = MFMA16(kf1, qf[fq][1], s);
          f32x4 a;
          a[0] = __expf(s[0]) * inv[fq];
          a[1] = __expf(s[1]) * inv[fq];
          a[2] = __expf(s[2]) * inv[fq];
          a[3] = __expf(s[3]) * inv[fq];
          *(f32x4*)(ah + (size_t)qrow * LSEQ + k0 + wk0 + fn * 16 + lg * 4) = a;
          u16x4 pk;
          pk[0] = f2bf(a[0]); pk[1] = f2bf(a[1]); pk[2] = f2bf(a[2]); pk[3] = f2bf(a[3]);
          *(u16x4*)&Ps[wid][fq * 16 + l15][fn * 16 + lg * 4] = pk;
        }
      }
    } else {
#pragma unroll
      for (int fn = 0; fn < 4; fn++) {
        const int krow = wk0 + fn * 16 + l15;
        const int rb = krow * 64, rx = (krow & 7) << 4;
        short8 kf0 = *(const short8*)&Ks[rb + (((lg * 16) ^ rx) >> 1)];
        short8 kf1 = *(const short8*)&Ks[rb + (((64 + lg * 16) ^ rx) >> 1)];
#pragma unroll
        for (int fq = 0; fq < 4; fq++) {
          const int qrow = wq0 + fq * 16 + l15;
          f32x4 s = (f32x4){0.f, 0.f, 0.f, 0.f};
          s = MFMA16(kf0, qf[fq][0], s);
          s = MFMA16(kf1, qf[fq][1], s);
          i32x4 m4 = *(const i32x4*)(mb + (size_t)qrow * LSEQ + k0 + wk0 + fn * 16 + lg * 4);
          f32x4 a;
          a[0] = (m4[0] != 0) ? __expf(s[0]) * inv[fq] : 0.f;
          a[1] = (m4[1] != 0) ? __expf(s[1]) * inv[fq] : 0.f;
          a[2] = (m4[2] != 0) ? __expf(s[2]) * inv[fq] : 0.f;
          a[3] = (m4[3] != 0) ? __expf(s[3]) * inv[fq] : 0.f;
          *(f32x4*)(ah + (size_t)qrow * LSEQ + k0 + wk0 + fn * 16 + lg * 4) = a;
          u16x4 pk;
          pk[0] = f2bf(a[0]); pk[1] = f2bf(a[1]); pk[2] = f2bf(a[2]); pk[3] = f2bf(a[3]);
          *(u16x4*)&Ps[wid][fq * 16 + l15][fn * 16 + lg * 4] = pk;
        }
      }
    }
    // PV: A = Ps rows (wave-private), B = V^T rows (registers)
    short8 pa2[4][2];
#pragma unroll
    for (int fq = 0; fq < 4; fq++)
#pragma unroll
      for (int ks = 0; ks < 2; ks++)
        pa2[fq][ks] = *(const short8*)&Ps[wid][fq * 16 + l15][ks * 32 + lg * 8];
#pragma unroll
    for (int fd = 0; fd < 4; fd++) {
#pragma unroll
      for (int fq = 0; fq < 4; fq++) {
        oacc[fq][fd] = MFMA16(pa2[fq][0], vf[fd][0], oacc[fq][fd]);
        oacc[fq][fd] = MFMA16(pa2[fq][1], vf[fd][1], oacc[fq][fd]);
      }
    }
  }

  // ---------------- k-split reduction + ctx store ----------------
  __syncthreads();  // Ps dead; reuse as fp32 reduction buffer (stride 65)
  float* red = (float*)&Ps[qw * 2][0][0];  // 2 buffers = 17408 B >= 64*65*4
  if (kw == 1) {
#pragma unroll
    for (int fq = 0; fq < 4; fq++)
#pragma unroll
      for (int fd = 0; fd < 4; fd++)
#pragma unroll
        for (int r = 0; r < 4; r++)
          red[(fq * 16 + lg * 4 + r) * 65 + fd * 16 + l15] = oacc[fq][fd][r];
  }
  __syncthreads();
  if (kw == 0) {
    unsigned short* ch = ctx + (size_t)b * LSEQ * DMOD + h * HDSZ;
#pragma unroll
    for (int fq = 0; fq < 4; fq++)
#pragma unroll
      for (int fd = 0; fd < 4; fd++)
#pragma unroll
        for (int r = 0; r < 4; r++) {
          const int qr = wq0 + fq * 16 + lg * 4 + r;
          const float o = oacc[fq][fd][r] + red[(fq * 16 + lg * 4 + r) * 65 + fd * 16 + l15];
          ch[(size_t)qr * DMOD + fd * 16 + l15] = f2bf(o);
        }
  }
}

// ---------------- launcher ----------------
extern "C" void kernel_launch(void* const* d_in, const int* in_sizes, int n_in,
                              void* d_out, int out_size, void* d_ws, size_t ws_size,
                              hipStream_t stream) {
  const float* q = (const float*)d_in[0];
  const float* k = (const float*)d_in[1];
  const float* v = (const float*)d_in[2];
  const int* mask = (const int*)d_in[3];
  const float* Wq = (const float*)d_in[4];
  const float* bq = (const float*)d_in[5];
  const float* Wk = (const float*)d_in[6];
  const float* bk = (const float*)d_in[7];
  const float* Wv = (const float*)d_in[8];
  const float* bv = (const float*)d_in[9];
  const float* Wo = (const float*)d_in[10];
  const float* bo = (const float*)d_in[11];

  float* out = (float*)d_out;
  float* attn = out + (size_t)BSZ * LSEQ * DMOD;

  const size_t NQKV = (size_t)BSZ * LSEQ * DMOD;
  const size_t NW = (size_t)DMOD * DMOD;

  // dead-before-attention scratch lives inside the attn output region
  unsigned short* qb = (unsigned short*)attn;
  unsigned short* kb = qb + NQKV;
  unsigned short* vb = kb + NQKV;
  unsigned short* Wqb = vb + NQKV;
  unsigned short* Wkb = Wqb + NW;
  unsigned short* Wvb = Wkb + NW;
  unsigned short* Vp = Wvb + NW;

  // flags live in the (not-yet-written) out region: consumed by attn,
  // overwritten by the final output projection.
  int* flags = (int*)out;  // 512 ints

  // survives attention -> d_ws
  unsigned short* Qp = (unsigned short*)d_ws;
  unsigned short* Kp = Qp + NQKV;
  unsigned short* Vt = Kp + NQKV;
  unsigned short* ctx = Vt + NQKV;
  unsigned short* Wob = ctx + NQKV;

  cvt_bf16<<<dim3(NQKV / 4 / 256), 256, 0, stream>>>(q, qb, (int)NQKV);
  cvt_bf16<<<dim3(NQKV / 4 / 256), 256, 0, stream>>>(k, kb, (int)NQKV);
  cvt_bf16<<<dim3(NQKV / 4 / 256), 256, 0, stream>>>(v, vb, (int)NQKV);
  cvt_bf16<<<dim3(NW / 4 / 256), 256, 0, stream>>>(Wq, Wqb, (int)NW);
  cvt_bf16<<<dim3(NW / 4 / 256), 256, 0, stream>>>(Wk, Wkb, (int)NW);
  cvt_bf16<<<dim3(NW / 4 / 256), 256, 0, stream>>>(Wv, Wvb, (int)NW);
  cvt_bf16<<<dim3(NW / 4 / 256), 256, 0, stream>>>(Wo, Wob, (int)NW);

  mask_check<<<dim3(16, 16, BSZ), 256, 0, stream>>>(mask, flags);

  gemm_bt<0><<<dim3(32, 8, 3), 256, 0, stream>>>(
      qb, kb, vb, Wqb, Wkb, Wvb, bq, bk, bv, (void*)Qp, (void*)Kp, (void*)Vp,
      0.125f, 1.0f, 1.0f, BSZ * LSEQ, DMOD, DMOD);

  transpose_v<<<dim3(LSEQ / 64, DMOD / 64, BSZ), 256, 0, stream>>>(Vp, Vt);

  attn_kernel<<<dim3(LSEQ / 128, BSZ * NH), 256, 0, stream>>>(Qp, Kp, Vt, mask, flags,
                                                              attn, ctx);

  gemm_bt<1><<<dim3(32, 8, 1), 256, 0, stream>>>(
      ctx, ctx, ctx, Wob, Wob, Wob, bo, bo, bo, (void*)out, (void*)out, (void*)out,
      1.0f, 1.0f, 1.0f, BSZ * LSEQ, DMOD, DMOD);
}

// Round 6
// 286.019 us; speedup vs baseline: 1.4597x; 1.0637x over previous
//
#include <hip/hip_runtime.h>
#include <stdint.h>

#define BSZ 2
#define LSEQ 2048
#define DMOD 1024
#define NH 16
#define HDSZ 64

typedef __attribute__((ext_vector_type(8))) short short8;
typedef __attribute__((ext_vector_type(4))) float f32x4;
typedef __attribute__((ext_vector_type(4))) unsigned short u16x4;
typedef __attribute__((ext_vector_type(4))) int i32x4;

#define MFMA16(a, b, c) __builtin_amdgcn_mfma_f32_16x16x32_bf16((a), (b), (c), 0, 0, 0)

__device__ __forceinline__ unsigned short f2bf(float f) {
  union { float f; unsigned u; } x; x.f = f;
  unsigned u = x.u + 0x7fffu + ((x.u >> 16) & 1u);
  return (unsigned short)(u >> 16);
}

__device__ __forceinline__ short8 pack8(f32x4 lo, f32x4 hi) {
  short8 o;
  o[0] = f2bf(lo[0]); o[1] = f2bf(lo[1]); o[2] = f2bf(lo[2]); o[3] = f2bf(lo[3]);
  o[4] = f2bf(hi[0]); o[5] = f2bf(hi[1]); o[6] = f2bf(hi[2]); o[7] = f2bf(hi[3]);
  return o;
}

// ---------------- mask check: flags[b][qt][kt] = all-nonzero over 128x128 tile ----
__global__ __launch_bounds__(256) void mask_check(const int* __restrict__ mask,
                                                  int* __restrict__ flags) {
  const int kt = blockIdx.x, qt = blockIdx.y, b = blockIdx.z;
  const int tid = threadIdx.x;
  const int r = tid >> 1, c = (tid & 1) * 64;
  const int* mr = mask + (size_t)b * LSEQ * LSEQ + (size_t)(qt * 128 + r) * LSEQ + kt * 128 + c;
  int ok = 1;
#pragma unroll
  for (int j = 0; j < 16; j++) {
    i32x4 v = __builtin_nontemporal_load((const i32x4*)(mr + j * 4));
    ok &= (v[0] != 0) & (v[1] != 0) & (v[2] != 0) & (v[3] != 0);
  }
  __shared__ int red[4];
  unsigned long long vote = __ballot(ok);
  if ((tid & 63) == 0) red[tid >> 6] = (vote == ~0ull) ? 1 : 0;
  __syncthreads();
  if (tid == 0) flags[(b * 16 + qt) * 16 + kt] = red[0] & red[1] & red[2] & red[3];
}

// ---------------- GEMM: C = A * W^T + bias --------------------------------------
// A: MxK (fp32 if AF32 else bf16), W: NxK fp32 (converted in-register), C per OUTF32.
// z==vtz: epilogue stores bf16 TRANSPOSED into (B, D, L) layout (fused V transpose).
template <int AF32, int OUTF32>
__global__ __launch_bounds__(256) void gemm_bt(
    const void* __restrict__ A0, const void* __restrict__ A1, const void* __restrict__ A2,
    const float* __restrict__ W0, const float* __restrict__ W1, const float* __restrict__ W2,
    const float* __restrict__ b0, const float* __restrict__ b1, const float* __restrict__ b2,
    void* __restrict__ C0, void* __restrict__ C1, void* __restrict__ C2,
    float s0, float s1, float s2, int vtz, int M, int N, int K) {
  const int z = blockIdx.z;
  const void* A = (z == 0) ? A0 : ((z == 1) ? A1 : A2);
  const float* W = (z == 0) ? W0 : ((z == 1) ? W1 : W2);
  const float* bias = (z == 0) ? b0 : ((z == 1) ? b1 : b2);
  void* Cout = (z == 0) ? C0 : ((z == 1) ? C1 : C2);
  const float scale = (z == 0) ? s0 : ((z == 1) ? s1 : s2);

  __shared__ unsigned short As[128 * 40];
  __shared__ unsigned short Bs[128 * 40];

  const int tid = threadIdx.x;
  const int lane = tid & 63;
  const int wid = tid >> 6;
  const int bm = blockIdx.x, bn = blockIdx.y;
  const int wm = (wid >> 1) * 64, wn = (wid & 1) * 64;

  f32x4 acc[4][4];
#pragma unroll
  for (int i = 0; i < 4; i++)
#pragma unroll
    for (int j = 0; j < 4; j++) acc[i][j] = (f32x4){0.f, 0.f, 0.f, 0.f};

  const int r0 = tid >> 2;
  const int c0 = (tid & 3) * 8;
  const float* Wg = W + (size_t)(bn * 128 + r0) * K + c0;

  // prefetch tile 0
  f32x4 vaf[2][2], vbf[2][2];
  short8 vah[2];
  if constexpr (AF32) {
    const float* Ag = (const float*)A + (size_t)(bm * 128 + r0) * K + c0;
#pragma unroll
    for (int j = 0; j < 2; j++) {
      vaf[j][0] = *(const f32x4*)(Ag + (size_t)(j * 64) * K);
      vaf[j][1] = *(const f32x4*)(Ag + (size_t)(j * 64) * K + 4);
    }
  } else {
    const unsigned short* Ag = (const unsigned short*)A + (size_t)(bm * 128 + r0) * K + c0;
#pragma unroll
    for (int j = 0; j < 2; j++) vah[j] = *(const short8*)(Ag + (size_t)(j * 64) * K);
  }
#pragma unroll
  for (int j = 0; j < 2; j++) {
    vbf[j][0] = *(const f32x4*)(Wg + (size_t)(j * 64) * K);
    vbf[j][1] = *(const f32x4*)(Wg + (size_t)(j * 64) * K + 4);
  }

  for (int k0 = 0; k0 < K; k0 += 32) {
#pragma unroll
    for (int j = 0; j < 2; j++) {
      if constexpr (AF32)
        *(short8*)&As[(j * 64 + r0) * 40 + c0] = pack8(vaf[j][0], vaf[j][1]);
      else
        *(short8*)&As[(j * 64 + r0) * 40 + c0] = vah[j];
      *(short8*)&Bs[(j * 64 + r0) * 40 + c0] = pack8(vbf[j][0], vbf[j][1]);
    }
    __syncthreads();
    if (k0 + 32 < K) {
      if constexpr (AF32) {
        const float* Ag = (const float*)A + (size_t)(bm * 128 + r0) * K + c0 + k0 + 32;
#pragma unroll
        for (int j = 0; j < 2; j++) {
          vaf[j][0] = *(const f32x4*)(Ag + (size_t)(j * 64) * K);
          vaf[j][1] = *(const f32x4*)(Ag + (size_t)(j * 64) * K + 4);
        }
      } else {
        const unsigned short* Ag =
            (const unsigned short*)A + (size_t)(bm * 128 + r0) * K + c0 + k0 + 32;
#pragma unroll
        for (int j = 0; j < 2; j++) vah[j] = *(const short8*)(Ag + (size_t)(j * 64) * K);
      }
#pragma unroll
      for (int j = 0; j < 2; j++) {
        vbf[j][0] = *(const f32x4*)(Wg + (size_t)(j * 64) * K + k0 + 32);
        vbf[j][1] = *(const f32x4*)(Wg + (size_t)(j * 64) * K + k0 + 36);
      }
    }
    short8 af[4], bf[4];
#pragma unroll
    for (int i = 0; i < 4; i++)
      af[i] = *(const short8*)&As[(wm + i * 16 + (lane & 15)) * 40 + (lane >> 4) * 8];
#pragma unroll
    for (int i = 0; i < 4; i++)
      bf[i] = *(const short8*)&Bs[(wn + i * 16 + (lane & 15)) * 40 + (lane >> 4) * 8];
#pragma unroll
    for (int i = 0; i < 4; i++)
#pragma unroll
      for (int j = 0; j < 4; j++) acc[i][j] = MFMA16(af[i], bf[j], acc[i][j]);
    __syncthreads();
  }

  const bool vtrans = (z == vtz);
  const int crow = bm * 128 + wm + ((lane >> 4) & 3) * 4;
#pragma unroll
  for (int j = 0; j < 4; j++) {
    const int col = bn * 128 + wn + j * 16 + (lane & 15);
    const float bv = bias[col];
#pragma unroll
    for (int i = 0; i < 4; i++) {
      if (OUTF32) {
#pragma unroll
        for (int r = 0; r < 4; r++) {
          float vvv = (acc[i][j][r] + bv) * scale;
          ((float*)Cout)[(size_t)(crow + i * 16 + r) * N + col] = vvv;
        }
      } else if (vtrans) {
        // V: store transposed into (B, D, L): Vt[row>>11][col][row&2047]
        u16x4 pk;
#pragma unroll
        for (int r = 0; r < 4; r++) pk[r] = f2bf((acc[i][j][r] + bv) * scale);
        const int row = crow + i * 16;
        unsigned short* dst = (unsigned short*)Cout +
                              (size_t)(row >> 11) * DMOD * LSEQ + (size_t)col * LSEQ +
                              (row & (LSEQ - 1));
        *(u16x4*)dst = pk;
      } else {
#pragma unroll
        for (int r = 0; r < 4; r++) {
          float vvv = (acc[i][j][r] + bv) * scale;
          ((unsigned short*)Cout)[(size_t)(crow + i * 16 + r) * N + col] = f2bf(vvv);
        }
      }
    }
  }
}

// ---------------- fused attention (v6 = v5 + nontemporal attn stores) ----------------
__global__ __launch_bounds__(256) void attn_kernel(
    const unsigned short* __restrict__ Qp, const unsigned short* __restrict__ Kp,
    const unsigned short* __restrict__ Vt, const int* __restrict__ mask,
    const int* __restrict__ flags, float* __restrict__ attn_out,
    unsigned short* __restrict__ ctx) {
  __shared__ unsigned short Ks[128 * 64];   // 16 KB, XOR-swizzled
  __shared__ unsigned short Ps[4][64][68];  // 34 KB
  __shared__ float denbuf[2][128];          // 1 KB

  const int tid = threadIdx.x, lane = tid & 63, wid = tid >> 6;
  const int kw = wid & 1, qw = wid >> 1;
  const int l15 = lane & 15, lg = lane >> 4;

  // XCD-aware remap: all 16 q-tiles of a head on one XCD (K/V L2-resident).
  const int wgid = blockIdx.x + gridDim.x * blockIdx.y;  // 0..511
  const int jj = wgid >> 3;                              // 0..63
  const int bh = (wgid & 7) * 4 + (jj >> 4);             // 0..31
  const int qt = jj & 15;                                // 0..15
  const int q0 = qt * 128;
  const int b = bh >> 4, h = bh & 15;

  const unsigned short* Qh = Qp + (size_t)b * LSEQ * DMOD + h * HDSZ;
  const unsigned short* Kh = Kp + (size_t)b * LSEQ * DMOD + h * HDSZ;
  const unsigned short* Vh = Vt + (size_t)b * DMOD * LSEQ + (size_t)h * HDSZ * LSEQ;
  const int* mb = mask + (size_t)b * LSEQ * LSEQ;
  const int* frow = flags + (b * 16 + qt) * 16;
  float* ah = attn_out + (size_t)bh * LSEQ * LSEQ;

  const int wq0 = q0 + qw * 64;
  const int wk0 = kw * 64;

  short8 qf[4][2];
#pragma unroll
  for (int fq = 0; fq < 4; fq++)
#pragma unroll
    for (int ks = 0; ks < 2; ks++)
      qf[fq][ks] = *(const short8*)(Qh + (size_t)(wq0 + fq * 16 + l15) * DMOD +
                                    ks * 32 + lg * 8);

  const int sr = tid >> 1;
  const unsigned short* Kst = Kh + (size_t)sr * DMOD + (tid & 1) * 32;
  const int swz_w = (sr & 7) << 4;

  // ---------------- sweep 1: denominators ----------------
  float den[4] = {0.f, 0.f, 0.f, 0.f};
  short8 ka[4];
#pragma unroll
  for (int j = 0; j < 4; j++) ka[j] = *(const short8*)(Kst + j * 8);

  for (int kt = 0; kt < LSEQ / 128; ++kt) {
    __syncthreads();
#pragma unroll
    for (int j = 0; j < 4; j++)
      *(short8*)&Ks[sr * 64 + (((((tid & 1) * 64) + j * 16) ^ swz_w) >> 1)] = ka[j];
    __syncthreads();
    if (kt + 1 < LSEQ / 128) {
#pragma unroll
      for (int j = 0; j < 4; j++)
        ka[j] = *(const short8*)(Kst + (size_t)(kt + 1) * 128 * DMOD + j * 8);
    }
    const bool fast = frow[kt] != 0;
    if (fast) {
#pragma unroll
      for (int fn = 0; fn < 4; fn++) {
        const int krow = wk0 + fn * 16 + l15;
        const int rb = krow * 64, rx = (krow & 7) << 4;
        short8 kf0 = *(const short8*)&Ks[rb + (((lg * 16) ^ rx) >> 1)];
        short8 kf1 = *(const short8*)&Ks[rb + (((64 + lg * 16) ^ rx) >> 1)];
#pragma unroll
        for (int fq = 0; fq < 4; fq++) {
          f32x4 s = (f32x4){0.f, 0.f, 0.f, 0.f};
          s = MFMA16(kf0, qf[fq][0], s);
          s = MFMA16(kf1, qf[fq][1], s);
          den[fq] += __expf(s[0]) + __expf(s[1]) + __expf(s[2]) + __expf(s[3]);
        }
      }
    } else {
      const int k0 = kt * 128;
#pragma unroll
      for (int fn = 0; fn < 4; fn++) {
        const int krow = wk0 + fn * 16 + l15;
        const int rb = krow * 64, rx = (krow & 7) << 4;
        short8 kf0 = *(const short8*)&Ks[rb + (((lg * 16) ^ rx) >> 1)];
        short8 kf1 = *(const short8*)&Ks[rb + (((64 + lg * 16) ^ rx) >> 1)];
#pragma unroll
        for (int fq = 0; fq < 4; fq++) {
          const int qrow = wq0 + fq * 16 + l15;
          f32x4 s = (f32x4){0.f, 0.f, 0.f, 0.f};
          s = MFMA16(kf0, qf[fq][0], s);
          s = MFMA16(kf1, qf[fq][1], s);
          i32x4 m4 = *(const i32x4*)(mb + (size_t)qrow * LSEQ + k0 + wk0 + fn * 16 + lg * 4);
          den[fq] += (m4[0] != 0) ? __expf(s[0]) : 0.f;
          den[fq] += (m4[1] != 0) ? __expf(s[1]) : 0.f;
          den[fq] += (m4[2] != 0) ? __expf(s[2]) : 0.f;
          den[fq] += (m4[3] != 0) ? __expf(s[3]) : 0.f;
        }
      }
    }
  }
#pragma unroll
  for (int fq = 0; fq < 4; fq++) {
    den[fq] += __shfl_xor(den[fq], 16);
    den[fq] += __shfl_xor(den[fq], 32);
  }
  if (lg == 0) {
#pragma unroll
    for (int fq = 0; fq < 4; fq++) denbuf[kw][qw * 64 + fq * 16 + l15] = den[fq];
  }
  __syncthreads();
  float inv[4];
#pragma unroll
  for (int fq = 0; fq < 4; fq++) {
    const int ql = qw * 64 + fq * 16 + l15;
    inv[fq] = 1.0f / (denbuf[0][ql] + denbuf[1][ql]);
  }

  // ---------------- sweep 2: attn write + PV ----------------
  f32x4 oacc[4][4];
#pragma unroll
  for (int fq = 0; fq < 4; fq++)
#pragma unroll
    for (int fd = 0; fd < 4; fd++) oacc[fq][fd] = (f32x4){0.f, 0.f, 0.f, 0.f};

#pragma unroll
  for (int j = 0; j < 4; j++) ka[j] = *(const short8*)(Kst + j * 8);

  const unsigned short* Vbase = Vh + (size_t)l15 * LSEQ + wk0 + lg * 8;

  for (int kt = 0; kt < LSEQ / 128; ++kt) {
    const int k0 = kt * 128;
    __syncthreads();
#pragma unroll
    for (int j = 0; j < 4; j++)
      *(short8*)&Ks[sr * 64 + (((((tid & 1) * 64) + j * 16) ^ swz_w) >> 1)] = ka[j];
    __syncthreads();
    short8 vf[4][2];
#pragma unroll
    for (int fd = 0; fd < 4; fd++)
#pragma unroll
      for (int ks = 0; ks < 2; ks++)
        vf[fd][ks] = *(const short8*)(Vbase + (size_t)(fd * 16) * LSEQ + k0 + ks * 32);
    if (kt + 1 < LSEQ / 128) {
#pragma unroll
      for (int j = 0; j < 4; j++)
        ka[j] = *(const short8*)(Kst + (size_t)(kt + 1) * 128 * DMOD + j * 8);
    }

    const bool fast = frow[kt] != 0;
    if (fast) {
#pragma unroll
      for (int fn = 0; fn < 4; fn++) {
        const int krow = wk0 + fn * 16 + l15;
        const int rb = krow * 64, rx = (krow & 7) << 4;
        short8 kf0 = *(const short8*)&Ks[rb + (((lg * 16) ^ rx) >> 1)];
        short8 kf1 = *(const short8*)&Ks[rb + (((64 + lg * 16) ^ rx) >> 1)];
#pragma unroll
        for (int fq = 0; fq < 4; fq++) {
          const int qrow = wq0 + fq * 16 + l15;
          f32x4 s = (f32x4){0.f, 0.f, 0.f, 0.f};
          s = MFMA16(kf0, qf[fq][0], s);
          s = MFMA16(kf1, qf[fq][1], s);
          f32x4 a;
          a[0] = __expf(s[0]) * inv[fq];
          a[1] = __expf(s[1]) * inv[fq];
          a[2] = __expf(s[2]) * inv[fq];
          a[3] = __expf(s[3]) * inv[fq];
          __builtin_nontemporal_store(
              a, (f32x4*)(ah + (size_t)qrow * LSEQ + k0 + wk0 + fn * 16 + lg * 4));
          u16x4 pk;
          pk[0] = f2bf(a[0]); pk[1] = f2bf(a[1]); pk[2] = f2bf(a[2]); pk[3] = f2bf(a[3]);
          *(u16x4*)&Ps[wid][fq * 16 + l15][fn * 16 + lg * 4] = pk;
        }
      }
    } else {
#pragma unroll
      for (int fn = 0; fn < 4; fn++) {
        const int krow = wk0 + fn * 16 + l15;
        const int rb = krow * 64, rx = (krow & 7) << 4;
        short8 kf0 = *(const short8*)&Ks[rb + (((lg * 16) ^ rx) >> 1)];
        short8 kf1 = *(const short8*)&Ks[rb + (((64 + lg * 16) ^ rx) >> 1)];
#pragma unroll
        for (int fq = 0; fq < 4; fq++) {
          const int qrow = wq0 + fq * 16 + l15;
          f32x4 s = (f32x4){0.f, 0.f, 0.f, 0.f};
          s = MFMA16(kf0, qf[fq][0], s);
          s = MFMA16(kf1, qf[fq][1], s);
          i32x4 m4 = *(const i32x4*)(mb + (size_t)qrow * LSEQ + k0 + wk0 + fn * 16 + lg * 4);
          f32x4 a;
          a[0] = (m4[0] != 0) ? __expf(s[0]) * inv[fq] : 0.f;
          a[1] = (m4[1] != 0) ? __expf(s[1]) * inv[fq] : 0.f;
          a[2] = (m4[2] != 0) ? __expf(s[2]) * inv[fq] : 0.f;
          a[3] = (m4[3] != 0) ? __expf(s[3]) * inv[fq] : 0.f;
          __builtin_nontemporal_store(
              a, (f32x4*)(ah + (size_t)qrow * LSEQ + k0 + wk0 + fn * 16 + lg * 4));
          u16x4 pk;
          pk[0] = f2bf(a[0]); pk[1] = f2bf(a[1]); pk[2] = f2bf(a[2]); pk[3] = f2bf(a[3]);
          *(u16x4*)&Ps[wid][fq * 16 + l15][fn * 16 + lg * 4] = pk;
        }
      }
    }
    short8 pa2[4][2];
#pragma unroll
    for (int fq = 0; fq < 4; fq++)
#pragma unroll
      for (int ks = 0; ks < 2; ks++)
        pa2[fq][ks] = *(const short8*)&Ps[wid][fq * 16 + l15][ks * 32 + lg * 8];
#pragma unroll
    for (int fd = 0; fd < 4; fd++) {
#pragma unroll
      for (int fq = 0; fq < 4; fq++) {
        oacc[fq][fd] = MFMA16(pa2[fq][0], vf[fd][0], oacc[fq][fd]);
        oacc[fq][fd] = MFMA16(pa2[fq][1], vf[fd][1], oacc[fq][fd]);
      }
    }
  }

  // ---------------- k-split reduction + ctx store ----------------
  __syncthreads();
  float* red = (float*)&Ps[qw * 2][0][0];
  if (kw == 1) {
#pragma unroll
    for (int fq = 0; fq < 4; fq++)
#pragma unroll
      for (int fd = 0; fd < 4; fd++)
#pragma unroll
        for (int r = 0; r < 4; r++)
          red[(fq * 16 + lg * 4 + r) * 65 + fd * 16 + l15] = oacc[fq][fd][r];
  }
  __syncthreads();
  if (kw == 0) {
    unsigned short* ch = ctx + (size_t)b * LSEQ * DMOD + h * HDSZ;
#pragma unroll
    for (int fq = 0; fq < 4; fq++)
#pragma unroll
      for (int fd = 0; fd < 4; fd++)
#pragma unroll
        for (int r = 0; r < 4; r++) {
          const int qr = wq0 + fq * 16 + lg * 4 + r;
          const float o = oacc[fq][fd][r] + red[(fq * 16 + lg * 4 + r) * 65 + fd * 16 + l15];
          ch[(size_t)qr * DMOD + fd * 16 + l15] = f2bf(o);
        }
  }
}

// ---------------- launcher ----------------
extern "C" void kernel_launch(void* const* d_in, const int* in_sizes, int n_in,
                              void* d_out, int out_size, void* d_ws, size_t ws_size,
                              hipStream_t stream) {
  const float* q = (const float*)d_in[0];
  const float* k = (const float*)d_in[1];
  const float* v = (const float*)d_in[2];
  const int* mask = (const int*)d_in[3];
  const float* Wq = (const float*)d_in[4];
  const float* bq = (const float*)d_in[5];
  const float* Wk = (const float*)d_in[6];
  const float* bk = (const float*)d_in[7];
  const float* Wv = (const float*)d_in[8];
  const float* bv = (const float*)d_in[9];
  const float* Wo = (const float*)d_in[10];
  const float* bo = (const float*)d_in[11];

  float* out = (float*)d_out;
  float* attn = out + (size_t)BSZ * LSEQ * DMOD;

  const size_t NQKV = (size_t)BSZ * LSEQ * DMOD;

  // flags live in the (not-yet-written) out region: consumed by attn,
  // overwritten by the final output projection.
  int* flags = (int*)out;  // 512 ints

  // survives attention -> d_ws
  unsigned short* Qp = (unsigned short*)d_ws;
  unsigned short* Kp = Qp + NQKV;
  unsigned short* Vt = Kp + NQKV;   // (B, D, L) -- written directly by fused gemm
  unsigned short* ctx = Vt + NQKV;

  mask_check<<<dim3(16, 16, BSZ), 256, 0, stream>>>(mask, flags);

  // QKV projections: fp32 inputs/weights converted in-register; V epilogue
  // stores transposed (fused transpose). 1/sqrt(HD)=0.125 folded into Q.
  gemm_bt<1, 0><<<dim3(32, 8, 3), 256, 0, stream>>>(
      q, k, v, Wq, Wk, Wv, bq, bk, bv, (void*)Qp, (void*)Kp, (void*)Vt,
      0.125f, 1.0f, 1.0f, /*vtz=*/2, BSZ * LSEQ, DMOD, DMOD);

  attn_kernel<<<dim3(LSEQ / 128, BSZ * NH), 256, 0, stream>>>(Qp, Kp, Vt, mask, flags,
                                                              attn, ctx);

  // output projection -> d_out
  gemm_bt<0, 1><<<dim3(32, 8, 1), 256, 0, stream>>>(
      ctx, ctx, ctx, Wo, Wo, Wo, bo, bo, bo, (void*)out, (void*)out, (void*)out,
      1.0f, 1.0f, 1.0f, /*vtz=*/-1, BSZ * LSEQ, DMOD, DMOD);
}